// Round 11
// baseline (95.549 us; speedup 1.0000x reference)
//
#include <hip/hip_runtime.h>

// SlidingKernelAttention: unfold(k=4,s=1) -> per-(b,c,patch-offset) attention
// over seq=256 tokens of dim=16 -> overlap-add fold.
// B=2, C=64, H=W=67, Ho=Wo=64, N = B*C*16 = 2048 independent sequences.
//
// R20: barrier-free all-register waves (R16's idea, budgeted to fit).
// Ledger: REP-marginal main loop 12.75us/rep == total issue (trans 10.2 +
// VALU 2.4) -> steady-state loop is issue-saturated. Residual ~23us idle
// is REP-independent (R17/R18) and occupancy-independent (R19 null). All
// prior structures share barrier-coupled waves (8 waves stall together at
// __syncthreads + shared lgkm/VMEM waits). R16 removed that but spilled
// (launch_bounds(1024,1) capped VGPR at 64 vs 96 needed).
// This round: one wave = one plane-sequence, NO barriers, NO shared data:
//  - kf[16]+vf[16] in VGPRs (64 regs); Q staged in wave-private LDS
//    (8KB/wave; same-wave ds_write->ds_read ordered by lgkmcnt, no
//    barrier); weights dead after projection. Live ~96-110 <= 128,
//    enforced by __launch_bounds__(256,4).
//  - 512 blocks x 256 thr = 2048 waves, whole grid co-resident at once
//    (2 blocks/CU; LDS 32KB/block), zero __syncthreads in the kernel.
//  - jq loop ROLLED (only t-indexed kf/vf need static indexing -> inner
//    #pragma unroll only; small I-cache). 2 q-tiles per jq step (ILP).
//  - per-wave coalesced f16 plane store (16.8MB); R0-style sum kernel
//    (16 reads/px, ~20MB, ~4-5us).
//
// MFMA layout identity (R5-R8): projection MFMA results ARE attention
// operands: K^T=Wk.X^T (A-frag), V=X.Wv^T (A-frag of V^T), Q^T=s.Wq.X^T
// (B-frag), P^T=exp2(S^T) (B-frag, in-register). X addressing
// (R13, HW-verified): lane (o,g) of tile t of plane (ii,jj) holds
// features 4g..4g+3 of token s=t*16+o at
//   x[bc][4t+(o>>2)+ii][16*(o&3)+4g+jj .. +3].
// ao layout (R0, HW-verified): ao[n][query*16+4g+idx], read as [64][64]:
// row hp=query>>2, col wp=(query&3)*16+4g+idx; out[bc][h][w] =
// sum_{i,j} ao[bc*16+i*4+j][h-i][w-j] (valid hp,wp in [0,64)).
// All fragments statically indexed (R4); f16 via v_cvt_pkrtz +
// bit_cast/shufflevector only (R8).
// Timed window includes the ~44-50us harness fill of d_ws (unavoidable).

#define BATCH 2
#define CHAN 64
#define HWDIM 67
#define DIM 16
#define PLANE 4096           // 64*64 = 256 queries x 16 dims per plane
#define OUT_TOTAL (BATCH * CHAN * HWDIM * HWDIM)   // 574592
#define ATT_SCALE 0.70710678118654752f             // (DIM/HEADS)^-0.5
#define LOG2E 1.44269504088896340736f

typedef _Float16 half4 __attribute__((ext_vector_type(4)));
typedef _Float16 half8 __attribute__((ext_vector_type(8)));
typedef float float4v __attribute__((ext_vector_type(4)));
typedef __fp16 fp16x2 __attribute__((ext_vector_type(2)));
typedef unsigned int uint2v __attribute__((ext_vector_type(2)));

// 2x v_cvt_pkrtz + register-pair aliasing: zero insert/extract VALU.
static __device__ __forceinline__ half4 mk_half4(float a, float b, float c, float d) {
    fp16x2 lo = __builtin_amdgcn_cvt_pkrtz(a, b);
    fp16x2 hi = __builtin_amdgcn_cvt_pkrtz(c, d);
    uint2v u;
    u[0] = __builtin_bit_cast(unsigned int, lo);
    u[1] = __builtin_bit_cast(unsigned int, hi);
    return __builtin_bit_cast(half4, u);
}

static __device__ __forceinline__ half4 pack4(float4v c) {
    return mk_half4(c[0], c[1], c[2], c[3]);
}

// one q-tile step: exp2 the 4 scores, accumulate denominator, pack,
// accumulate O^T.
static __device__ __forceinline__ void att_step(const half4 vf, const float4v sfr,
                                                float& l, float4v& oacc) {
    const float p0 = __builtin_amdgcn_exp2f(sfr[0]);
    const float p1 = __builtin_amdgcn_exp2f(sfr[1]);
    const float p2 = __builtin_amdgcn_exp2f(sfr[2]);
    const float p3 = __builtin_amdgcn_exp2f(sfr[3]);
    l += (p0 + p1) + (p2 + p3);
    const half4 pb = mk_half4(p0, p1, p2, p3);
    oacc = __builtin_amdgcn_mfma_f32_16x16x16f16(vf, pb, oacc, 0, 0, 0);
}

__global__ __launch_bounds__(256, 4) void ska_attn(
    const float* __restrict__ x,      // [B, C, 67, 67]
    const float* __restrict__ w,      // [48, 16]
    _Float16* __restrict__ ao)        // [NSEQ=2048, 256, 16] f16 in d_ws
{
    // wave-private Q strips: qlds[wave][t][lane] = half4 Q^T B-frag.
    // Same-wave write->read only (lgkmcnt-ordered): NO barrier needed.
    __shared__ __align__(16) _Float16 qlds[4][16][64][4];   // 32 KB

    // XCD chunked swizzle: 512 blocks = 8 XCDs x 64 -> bc [16k,16k+16) on
    // XCD k (the 4 waves of a block + sibling blocks share x[bc] in L2).
    const int b  = (int)(blockIdx.x & 7) * 64 + (int)(blockIdx.x >> 3);
    const int bc = b >> 2;
    const int ii = b & 3;          // patch-row offset

    const int tid  = threadIdx.x;
    const int wave = tid >> 6;     // = jj: patch-col offset (one plane/wave)
    const int lane = tid & 63;
    const int o = lane & 15;       // token-in-tile / weight output row
    const int g = lane >> 4;       // feature group (k-group)
    const int jj = wave;

    // weight fragments straight from global (3 KB, L1-resident).
    // wq/wk/wv frags are DEAD after the projection loop (frees 6 VGPR).
    const float4 wq4 = *(const float4*)(w + ( 0 + o) * DIM + 4 * g);
    const float4 wk4 = *(const float4*)(w + (16 + o) * DIM + 4 * g);
    const float4 wv4 = *(const float4*)(w + (32 + o) * DIM + 4 * g);
    const half4 wqf = mk_half4(wq4.x * (ATT_SCALE * LOG2E), wq4.y * (ATT_SCALE * LOG2E),
                               wq4.z * (ATT_SCALE * LOG2E), wq4.w * (ATT_SCALE * LOG2E));
    const half4 wkf = mk_half4(wk4.x, wk4.y, wk4.z, wk4.w);
    const half4 wvf = mk_half4(wv4.x, wv4.y, wv4.z, wv4.w);

    const float4v zf = (float4v){0.f, 0.f, 0.f, 0.f};

    // projection: X direct-to-register (R13 addressing), K/V fragments
    // stay in VGPRs for the whole kernel; Q goes to the wave-private strip.
    const float* xb = x + ((size_t)bc * HWDIM + ii) * HWDIM + (o & 3) * 16 + 4 * g + jj;
    half4 kf[16], vf[16];
#pragma unroll
    for (int t = 0; t < 16; ++t) {
        const float* xp = xb + (4 * t + (o >> 2)) * HWDIM;
        const half4 xf = mk_half4(xp[0], xp[1], xp[2], xp[3]);
        kf[t] = pack4(__builtin_amdgcn_mfma_f32_16x16x16f16(wkf, xf, zf, 0, 0, 0));
        vf[t] = pack4(__builtin_amdgcn_mfma_f32_16x16x16f16(xf, wvf, zf, 0, 0, 0));
        const half4 qf = pack4(__builtin_amdgcn_mfma_f32_16x16x16f16(wqf, xf, zf, 0, 0, 0));
        *(half4*)&qlds[wave][t][lane][0] = qf;
    }

    const int n = bc * 16 + ii * 4 + jj;
    _Float16* aop = ao + (size_t)n * PLANE;

    // attention: jq ROLLED (qlds/store indices may be runtime); inner t
    // UNROLLED (kf[t]/vf[t] must be static register indices). 2 q-tiles
    // per step for ILP. No barriers anywhere; waves fully independent.
    for (int jq = 0; jq < 16; jq += 2) {
        const half4 qp0 = *(const half4*)&qlds[wave][jq][lane][0];
        const half4 qp1 = *(const half4*)&qlds[wave][jq + 1][lane][0];
        float4v oacc0 = zf, oacc1 = zf;
        float l0 = 0.f, l1 = 0.f;
#pragma unroll
        for (int t = 0; t < 16; ++t) {
            const float4v s0 = __builtin_amdgcn_mfma_f32_16x16x16f16(kf[t], qp0, zf, 0, 0, 0);
            const float4v s1 = __builtin_amdgcn_mfma_f32_16x16x16f16(kf[t], qp1, zf, 0, 0, 0);
            att_step(vf[t], s0, l0, oacc0);
            att_step(vf[t], s1, l1, oacc1);
        }
        // denominator reduce + coalesced f16 store of the two q-tiles
#pragma unroll
        for (int u = 0; u < 2; ++u) {
            float lj = u ? l1 : l0;
            lj += __shfl_xor(lj, 16, 64);
            lj += __shfl_xor(lj, 32, 64);
            const float rl = __builtin_amdgcn_rcpf(lj);
            const float4v oa = u ? oacc1 : oacc0;
            const int query = (jq + u) * 16 + o;
            *(half4*)(aop + query * DIM + 4 * g) =
                mk_half4(oa[0] * rl, oa[1] * rl, oa[2] * rl, oa[3] * rl);
        }
    }
}

// sum kernel: out[bc][h][w] = sum_{i,j} ao[bc*16+i*4+j][h-i][w-j]
// with ao-as-[64][64]: linear = q*16+d, q = hp*4 + (wp>>4), d = wp&15.
__global__ __launch_bounds__(256) void ska_sum(
    const _Float16* __restrict__ ao,
    float* __restrict__ out)
{
    const int idx = (int)(blockIdx.x * 256 + threadIdx.x);
    if (idx >= OUT_TOTAL) return;
    const int bc  = idx / (HWDIM * HWDIM);
    const int rem = idx % (HWDIM * HWDIM);
    const int h   = rem / HWDIM;
    const int ww  = rem % HWDIM;
    float acc = 0.f;
#pragma unroll
    for (int i = 0; i < 4; ++i) {
        const int hp = h - i;
        if (hp < 0 || hp >= 64) continue;
#pragma unroll
        for (int j = 0; j < 4; ++j) {
            const int wp = ww - j;
            if (wp < 0 || wp >= 64) continue;
            const int n = bc * 16 + i * 4 + j;
            const int q = (hp << 2) + (wp >> 4);
            const int d = wp & 15;
            acc += (float)ao[(size_t)n * PLANE + q * DIM + d];
        }
    }
    out[idx] = acc;
}

// ---- fallback (R17 single-kernel atomic merge) if workspace too small ----
__global__ __launch_bounds__(512, 4) void ska_fused_atomic(
    const float* __restrict__ x, const float* __restrict__ w,
    float* __restrict__ out)
{
    __shared__ __align__(16) _Float16 buf[2][16][64][8];
    __shared__ float fold[64][69];

    const int b  = (int)(blockIdx.x & 7) * 64 + (int)(blockIdx.x >> 3);
    const int bc = b >> 2;
    const int ii = b & 3;
    const int tid  = threadIdx.x;
    const int wave = tid >> 6;
    const int lane = tid & 63;
    const int o = lane & 15;
    const int g = lane >> 4;

    {
        float* ff = &fold[0][0];
        for (int i = tid; i < 64 * 69; i += 512) ff[i] = 0.f;
    }

    const float4 wq4 = *(const float4*)(w + ( 0 + o) * DIM + 4 * g);
    const float4 wk4 = *(const float4*)(w + (16 + o) * DIM + 4 * g);
    const float4 wv4 = *(const float4*)(w + (32 + o) * DIM + 4 * g);
    const half4 wqf = mk_half4(wq4.x * (ATT_SCALE * LOG2E), wq4.y * (ATT_SCALE * LOG2E),
                               wq4.z * (ATT_SCALE * LOG2E), wq4.w * (ATT_SCALE * LOG2E));
    const half4 wkf = mk_half4(wk4.x, wk4.y, wk4.z, wk4.w);
    const half4 wvf = mk_half4(wv4.x, wv4.y, wv4.z, wv4.w);
    const float4v zf = (float4v){0.f, 0.f, 0.f, 0.f};

    const float* xb = x + ((size_t)bc * HWDIM + ii) * HWDIM + (o & 3) * 16 + 4 * g;
    const int roff0 = (8 * wave + (o >> 2)) * HWDIM;
    const int roff1 = roff0 + 4 * HWDIM;

    float xr0a = xb[roff0 + 0], xr0b = xb[roff0 + 1],
          xr0c = xb[roff0 + 2], xr0d = xb[roff0 + 3];
    float xr1a = xb[roff1 + 0], xr1b = xb[roff1 + 1],
          xr1c = xb[roff1 + 2], xr1d = xb[roff1 + 3];

    for (int jj = 0; jj < 4; ++jj) {
        const int cur = jj & 1;
        half4 qfr0, qfr1;
        {
            const half4 xf0 = mk_half4(xr0a, xr0b, xr0c, xr0d);
            const half4 kf0 = pack4(__builtin_amdgcn_mfma_f32_16x16x16f16(wkf, xf0, zf, 0, 0, 0));
            const half4 vf0 = pack4(__builtin_amdgcn_mfma_f32_16x16x16f16(xf0, wvf, zf, 0, 0, 0));
            *(half8*)&buf[cur][2 * wave][lane][0] =
                __builtin_shufflevector(kf0, vf0, 0, 1, 2, 3, 4, 5, 6, 7);
            qfr0 = pack4(__builtin_amdgcn_mfma_f32_16x16x16f16(wqf, xf0, zf, 0, 0, 0));
            const half4 xf1 = mk_half4(xr1a, xr1b, xr1c, xr1d);
            const half4 kf1 = pack4(__builtin_amdgcn_mfma_f32_16x16x16f16(wkf, xf1, zf, 0, 0, 0));
            const half4 vf1 = pack4(__builtin_amdgcn_mfma_f32_16x16x16f16(xf1, wvf, zf, 0, 0, 0));
            *(half8*)&buf[cur][2 * wave + 1][lane][0] =
                __builtin_shufflevector(kf1, vf1, 0, 1, 2, 3, 4, 5, 6, 7);
            qfr1 = pack4(__builtin_amdgcn_mfma_f32_16x16x16f16(wqf, xf1, zf, 0, 0, 0));
        }
        if (jj < 3) {
            const int d = jj + 1;
            xr0a = xb[roff0 + d + 0]; xr0b = xb[roff0 + d + 1];
            xr0c = xb[roff0 + d + 2]; xr0d = xb[roff0 + d + 3];
            xr1a = xb[roff1 + d + 0]; xr1b = xb[roff1 + d + 1];
            xr1c = xb[roff1 + d + 2]; xr1d = xb[roff1 + d + 3];
        }
        __syncthreads();

        float4v oacc0 = zf, oacc1 = zf;
        float l0 = 0.f, l1 = 0.f;
        half8 kvc = *(const half8*)&buf[cur][0][lane][0];
#pragma unroll 4
        for (int t = 0; t < 16; ++t) {
            const half8 kvn = *(const half8*)&buf[cur][(t + 1) & 15][lane][0];
            const half4 kf = __builtin_shufflevector(kvc, kvc, 0, 1, 2, 3);
            const half4 vf = __builtin_shufflevector(kvc, kvc, 4, 5, 6, 7);
            const float4v s0 = __builtin_amdgcn_mfma_f32_16x16x16f16(kf, qfr0, zf, 0, 0, 0);
            const float4v s1 = __builtin_amdgcn_mfma_f32_16x16x16f16(kf, qfr1, zf, 0, 0, 0);
            att_step(vf, s0, l0, oacc0);
            att_step(vf, s1, l1, oacc1);
            kvc = kvn;
        }
#pragma unroll
        for (int u = 0; u < 2; ++u) {
            float lj = u ? l1 : l0;
            lj += __shfl_xor(lj, 16, 64);
            lj += __shfl_xor(lj, 32, 64);
            const float rl = __builtin_amdgcn_rcpf(lj);
            const float4v oa = u ? oacc1 : oacc0;
            const int r = 8 * wave + 4 * u + (o >> 2);
            const int c = 16 * (o & 3) + 4 * g + jj;
            fold[r][c + 0] += oa[0] * rl;
            fold[r][c + 1] += oa[1] * rl;
            fold[r][c + 2] += oa[2] * rl;
            fold[r][c + 3] += oa[3] * rl;
        }
    }
    __syncthreads();

    float* ob = out + ((size_t)bc * HWDIM + ii) * HWDIM;
    for (int i = tid; i < 64 * HWDIM; i += 512) {
        atomicAdd(&ob[i], fold[i / HWDIM][i % HWDIM]);
    }
}

extern "C" void kernel_launch(void* const* d_in, const int* in_sizes, int n_in,
                              void* d_out, int out_size, void* d_ws, size_t ws_size,
                              hipStream_t stream) {
    const float* x = (const float*)d_in[0];
    const float* w = (const float*)d_in[1];
    float* out = (float*)d_out;
    (void)in_sizes; (void)n_in;

    const size_t need = (size_t)BATCH * CHAN * 16 * PLANE * sizeof(_Float16); // 16.8 MB
    if (ws_size >= need) {
        _Float16* ao = (_Float16*)d_ws;
        ska_attn<<<BATCH * CHAN * 4, 256, 0, stream>>>(x, w, ao);
        ska_sum<<<(OUT_TOTAL + 255) / 256, 256, 0, stream>>>(ao, out);
    } else {
        (void)hipMemsetAsync(out, 0, (size_t)out_size * sizeof(float), stream);
        ska_fused_atomic<<<BATCH * CHAN * 4, 512, 0, stream>>>(x, w, out);
    }
}

// Round 12
// 95.505 us; speedup vs baseline: 1.0005x; 1.0005x over previous
//
#include <hip/hip_runtime.h>

// SlidingKernelAttention: unfold(k=4,s=1) -> per-(b,c,patch-offset) attention
// over seq=256 tokens of dim=16 -> overlap-add fold.
// B=2, C=64, H=W=67, Ho=Wo=64, N = B*C*16 = 2048 independent sequences.
//
// R21: barrier-free register-resident waves at 4 waves/SIMD. R20 (1 wave =
// 1 plane) regressed to 51us controllable, but was confounded: 2048 waves
// = only 2 waves/SIMD, too few to hide the S-MFMA->exp2->pack->O-MFMA
// chain. Ledger refit: REP-marginal 12.75us == 2.1M wave64 exp2 at ~14.9
// cyc/instr -> main loop is ~100% trans-pipe-bound (floor ~13us); the
// target is the ~26us REP-independent residue whose surviving suspects
// (generation tail / ds_read chains / barrier alignment) are all absent
// only in a barrier-free >=4-wave/SIMD design:
//  - wave = (plane, query-half): 8 q-tiles per wave, all 16 K/V tiles in
//    VGPRs (kf[16]+vf[16] = 64 regs; K/V proj duplicated 2x per plane).
//    4096 waves = 1024 blocks x 256 thr = 4 blocks/CU (16KB LDS), ONE
//    generation, 4 waves/SIMD, zero __syncthreads, zero main-loop LDS.
//  - softmax denominator via ones-MFMA: lacc = mfma(ones, pb, lacc);
//    D = 1*P^T makes every lane hold the full 16-key column sum for its
//    query o; accumulated over t it is the COMPLETE l (the MFMA k-dim
//    spans all 4 g-group quarters) -> kills 3 VALU adds/step AND the
//    final shfl_xor reduce. Uses the idle MFMA pipe (33% util).
//  - Q staged in wave-private LDS (4KB/wave; same-wave ds ordering, no
//    barrier). VGPR ~106 <= 128 via __launch_bounds__(256,4).
//
// MFMA layout identity (R5-R8, HW-verified): projection MFMA results ARE
// attention operands: K^T=Wk.X^T (A-frag), V=X.Wv^T (A-frag of V^T),
// Q^T=s.Wq.X^T (B-frag), P^T=exp2(S^T) (B-frag). C/D layout == B layout:
// lane (o,g) reg idx holds D[4g+idx][o]; for D=ones*P^T every reg = l_o.
// X addressing (R13): lane (o,g) of tile t of plane (ii,jj) holds
// features 4g..4g+3 of token s=t*16+o at
//   x[bc][4t+(o>>2)+ii][16*(o&3)+4g+jj .. +3].
// ao layout (R0/R20, HW-verified): ao[n][query*16+4g+idx] read as [64][64]
// (row hp=query>>2, col wp=(query&3)*16+4g+idx); out[bc][h][w] =
// sum_{i,j} ao[bc*16+i*4+j][h-i][w-j]. All fragments statically indexed
// (R4); f16 via v_cvt_pkrtz + bit_cast/shufflevector only (R8).
// Timed window includes the ~44-50us harness fill of d_ws (unavoidable).

#define BATCH 2
#define CHAN 64
#define HWDIM 67
#define DIM 16
#define PLANE 4096           // 64*64 = 256 queries x 16 dims per plane
#define OUT_TOTAL (BATCH * CHAN * HWDIM * HWDIM)   // 574592
#define ATT_SCALE 0.70710678118654752f             // (DIM/HEADS)^-0.5
#define LOG2E 1.44269504088896340736f

typedef _Float16 half4 __attribute__((ext_vector_type(4)));
typedef _Float16 half8 __attribute__((ext_vector_type(8)));
typedef float float4v __attribute__((ext_vector_type(4)));
typedef __fp16 fp16x2 __attribute__((ext_vector_type(2)));
typedef unsigned int uint2v __attribute__((ext_vector_type(2)));

// 2x v_cvt_pkrtz + register-pair aliasing: zero insert/extract VALU.
static __device__ __forceinline__ half4 mk_half4(float a, float b, float c, float d) {
    fp16x2 lo = __builtin_amdgcn_cvt_pkrtz(a, b);
    fp16x2 hi = __builtin_amdgcn_cvt_pkrtz(c, d);
    uint2v u;
    u[0] = __builtin_bit_cast(unsigned int, lo);
    u[1] = __builtin_bit_cast(unsigned int, hi);
    return __builtin_bit_cast(half4, u);
}

static __device__ __forceinline__ half4 pack4(float4v c) {
    return mk_half4(c[0], c[1], c[2], c[3]);
}

// one q-tile step: exp2 the 4 scores, pack, accumulate O^T and (via the
// ones-MFMA) the softmax denominator. No VALU l-adds.
static __device__ __forceinline__ void att_step2(const half4 vf, const half4 ones,
                                                 const float4v sfr,
                                                 float4v& lacc, float4v& oacc) {
    const float p0 = __builtin_amdgcn_exp2f(sfr[0]);
    const float p1 = __builtin_amdgcn_exp2f(sfr[1]);
    const float p2 = __builtin_amdgcn_exp2f(sfr[2]);
    const float p3 = __builtin_amdgcn_exp2f(sfr[3]);
    const half4 pb = mk_half4(p0, p1, p2, p3);
    oacc = __builtin_amdgcn_mfma_f32_16x16x16f16(vf, pb, oacc, 0, 0, 0);
    lacc = __builtin_amdgcn_mfma_f32_16x16x16f16(ones, pb, lacc, 0, 0, 0);
}

__global__ __launch_bounds__(256, 4) void ska_attn(
    const float* __restrict__ x,      // [B, C, 67, 67]
    const float* __restrict__ w,      // [48, 16]
    _Float16* __restrict__ ao)        // [2048, 256, 16] f16 in d_ws
{
    // wave-private Q strips: qlds[wave][u][lane] = half4 Q^T B-frag for
    // the wave's u-th q-tile. Same-wave write->read (lgkmcnt-ordered):
    // NO barrier anywhere in this kernel.
    __shared__ __align__(16) _Float16 qlds[4][8][64][4];   // 16 KB

    // XCD chunked swizzle: 1024 blocks = 8 XCDs x 128 -> bc [16k,16k+16)
    // on XCD k. b -> (bc, ii, bh); wave task = bh*4+wave -> (jj, qh).
    const int b  = (int)(blockIdx.x & 7) * 128 + (int)(blockIdx.x >> 3);
    const int bc = b >> 3;
    const int ii = (b >> 1) & 3;   // patch-row offset
    const int bh = b & 1;          // which 4 of the 8 (jj,qh) tasks

    const int tid  = threadIdx.x;
    const int wave = tid >> 6;
    const int lane = tid & 63;
    const int o = lane & 15;       // token-in-tile / weight output row
    const int g = lane >> 4;       // feature group (k-group)
    const int task = bh * 4 + wave;
    const int jj = task >> 1;      // patch-col offset (plane)
    const int qh = task & 1;       // query half: q-tiles [8*qh, 8*qh+8)

    // weight fragments straight from global (3 KB, L1-resident); dead
    // after projection.
    const float4 wq4 = *(const float4*)(w + ( 0 + o) * DIM + 4 * g);
    const float4 wk4 = *(const float4*)(w + (16 + o) * DIM + 4 * g);
    const float4 wv4 = *(const float4*)(w + (32 + o) * DIM + 4 * g);
    const half4 wqf = mk_half4(wq4.x * (ATT_SCALE * LOG2E), wq4.y * (ATT_SCALE * LOG2E),
                               wq4.z * (ATT_SCALE * LOG2E), wq4.w * (ATT_SCALE * LOG2E));
    const half4 wkf = mk_half4(wk4.x, wk4.y, wk4.z, wk4.w);
    const half4 wvf = mk_half4(wv4.x, wv4.y, wv4.z, wv4.w);

    const float4v zf = (float4v){0.f, 0.f, 0.f, 0.f};

    // projection. X direct-to-register (R13 addressing). K/V: all 16
    // tiles -> VGPRs (duplicated across the 2 waves of this plane; the
    // sibling's loads are L1 hits). Q: own 8 tiles -> wave-private LDS.
    const float* xb = x + ((size_t)bc * HWDIM + ii) * HWDIM + (o & 3) * 16 + 4 * g + jj;
    half4 kf[16], vf[16];
#pragma unroll
    for (int t = 0; t < 16; ++t) {
        const float* xp = xb + (4 * t + (o >> 2)) * HWDIM;
        const half4 xf = mk_half4(xp[0], xp[1], xp[2], xp[3]);
        kf[t] = pack4(__builtin_amdgcn_mfma_f32_16x16x16f16(wkf, xf, zf, 0, 0, 0));
        vf[t] = pack4(__builtin_amdgcn_mfma_f32_16x16x16f16(xf, wvf, zf, 0, 0, 0));
    }
#pragma unroll
    for (int u = 0; u < 8; ++u) {
        const int t = 8 * qh + u;
        const float* xp = xb + (4 * t + (o >> 2)) * HWDIM;   // L1 re-hit
        const half4 xf = mk_half4(xp[0], xp[1], xp[2], xp[3]);
        const half4 qf = pack4(__builtin_amdgcn_mfma_f32_16x16x16f16(wqf, xf, zf, 0, 0, 0));
        *(half4*)&qlds[wave][u][lane][0] = qf;
    }

    const int n = bc * 16 + ii * 4 + jj;
    _Float16* aop = ao + (size_t)n * PLANE;
    const half4 ones = {(_Float16)1.f, (_Float16)1.f, (_Float16)1.f, (_Float16)1.f};

    // attention: 4 jq-pair iterations (2 q-tiles each for ILP), 16 k-tiles
    // per pair, all operands register-resident. No barriers; waves fully
    // independent; 4 waves/SIMD hide the MFMA->exp2->pack->MFMA chains.
#pragma unroll
    for (int jp = 0; jp < 4; ++jp) {
        const half4 qp0 = *(const half4*)&qlds[wave][2 * jp][lane][0];
        const half4 qp1 = *(const half4*)&qlds[wave][2 * jp + 1][lane][0];
        float4v oacc0 = zf, oacc1 = zf, lacc0 = zf, lacc1 = zf;
#pragma unroll
        for (int t = 0; t < 16; ++t) {
            const float4v s0 = __builtin_amdgcn_mfma_f32_16x16x16f16(kf[t], qp0, zf, 0, 0, 0);
            const float4v s1 = __builtin_amdgcn_mfma_f32_16x16x16f16(kf[t], qp1, zf, 0, 0, 0);
            att_step2(vf[t], ones, s0, lacc0, oacc0);
            att_step2(vf[t], ones, s1, lacc1, oacc1);
        }
        // l is complete in every lacc reg (ones-MFMA spans all 16 keys of
        // each tile, i.e. all 4 g-quarters): no cross-lane reduce needed.
#pragma unroll
        for (int u = 0; u < 2; ++u) {
            const float4v oa = u ? oacc1 : oacc0;
            const float lj  = u ? lacc1[0] : lacc0[0];
            const float rl = __builtin_amdgcn_rcpf(lj);
            const int query = (8 * qh + 2 * jp + u) * 16 + o;
            *(half4*)(aop + query * DIM + 4 * g) =
                mk_half4(oa[0] * rl, oa[1] * rl, oa[2] * rl, oa[3] * rl);
        }
    }
}

// sum kernel: out[bc][h][w] = sum_{i,j} ao[bc*16+i*4+j][h-i][w-j]
// with ao-as-[64][64]: q = hp*4 + (wp>>4), d = wp&15.
__global__ __launch_bounds__(256) void ska_sum(
    const _Float16* __restrict__ ao,
    float* __restrict__ out)
{
    const int idx = (int)(blockIdx.x * 256 + threadIdx.x);
    if (idx >= OUT_TOTAL) return;
    const int bc  = idx / (HWDIM * HWDIM);
    const int rem = idx % (HWDIM * HWDIM);
    const int h   = rem / HWDIM;
    const int ww  = rem % HWDIM;
    float acc = 0.f;
#pragma unroll
    for (int i = 0; i < 4; ++i) {
        const int hp = h - i;
        if (hp < 0 || hp >= 64) continue;
#pragma unroll
        for (int j = 0; j < 4; ++j) {
            const int wp = ww - j;
            if (wp < 0 || wp >= 64) continue;
            const int n = bc * 16 + i * 4 + j;
            const int q = (hp << 2) + (wp >> 4);
            const int d = wp & 15;
            acc += (float)ao[(size_t)n * PLANE + q * DIM + d];
        }
    }
    out[idx] = acc;
}

// ---- fallback (R17 single-kernel atomic merge) if workspace too small ----
__global__ __launch_bounds__(512, 4) void ska_fused_atomic(
    const float* __restrict__ x, const float* __restrict__ w,
    float* __restrict__ out)
{
    __shared__ __align__(16) _Float16 buf[2][16][64][8];
    __shared__ float fold[64][69];

    const int b  = (int)(blockIdx.x & 7) * 64 + (int)(blockIdx.x >> 3);
    const int bc = b >> 2;
    const int ii = b & 3;
    const int tid  = threadIdx.x;
    const int wave = tid >> 6;
    const int lane = tid & 63;
    const int o = lane & 15;
    const int g = lane >> 4;

    {
        float* ff = &fold[0][0];
        for (int i = tid; i < 64 * 69; i += 512) ff[i] = 0.f;
    }

    const float4 wq4 = *(const float4*)(w + ( 0 + o) * DIM + 4 * g);
    const float4 wk4 = *(const float4*)(w + (16 + o) * DIM + 4 * g);
    const float4 wv4 = *(const float4*)(w + (32 + o) * DIM + 4 * g);
    const half4 wqf = mk_half4(wq4.x * (ATT_SCALE * LOG2E), wq4.y * (ATT_SCALE * LOG2E),
                               wq4.z * (ATT_SCALE * LOG2E), wq4.w * (ATT_SCALE * LOG2E));
    const half4 wkf = mk_half4(wk4.x, wk4.y, wk4.z, wk4.w);
    const half4 wvf = mk_half4(wv4.x, wv4.y, wv4.z, wv4.w);
    const float4v zf = (float4v){0.f, 0.f, 0.f, 0.f};

    const float* xb = x + ((size_t)bc * HWDIM + ii) * HWDIM + (o & 3) * 16 + 4 * g;
    const int roff0 = (8 * wave + (o >> 2)) * HWDIM;
    const int roff1 = roff0 + 4 * HWDIM;

    float xr0a = xb[roff0 + 0], xr0b = xb[roff0 + 1],
          xr0c = xb[roff0 + 2], xr0d = xb[roff0 + 3];
    float xr1a = xb[roff1 + 0], xr1b = xb[roff1 + 1],
          xr1c = xb[roff1 + 2], xr1d = xb[roff1 + 3];

    for (int jj = 0; jj < 4; ++jj) {
        const int cur = jj & 1;
        half4 qfr0, qfr1;
        {
            const half4 xf0 = mk_half4(xr0a, xr0b, xr0c, xr0d);
            const half4 kf0 = pack4(__builtin_amdgcn_mfma_f32_16x16x16f16(wkf, xf0, zf, 0, 0, 0));
            const half4 vf0 = pack4(__builtin_amdgcn_mfma_f32_16x16x16f16(xf0, wvf, zf, 0, 0, 0));
            *(half8*)&buf[cur][2 * wave][lane][0] =
                __builtin_shufflevector(kf0, vf0, 0, 1, 2, 3, 4, 5, 6, 7);
            qfr0 = pack4(__builtin_amdgcn_mfma_f32_16x16x16f16(wqf, xf0, zf, 0, 0, 0));
            const half4 xf1 = mk_half4(xr1a, xr1b, xr1c, xr1d);
            const half4 kf1 = pack4(__builtin_amdgcn_mfma_f32_16x16x16f16(wkf, xf1, zf, 0, 0, 0));
            const half4 vf1 = pack4(__builtin_amdgcn_mfma_f32_16x16x16f16(xf1, wvf, zf, 0, 0, 0));
            *(half8*)&buf[cur][2 * wave + 1][lane][0] =
                __builtin_shufflevector(kf1, vf1, 0, 1, 2, 3, 4, 5, 6, 7);
            qfr1 = pack4(__builtin_amdgcn_mfma_f32_16x16x16f16(wqf, xf1, zf, 0, 0, 0));
        }
        if (jj < 3) {
            const int d = jj + 1;
            xr0a = xb[roff0 + d + 0]; xr0b = xb[roff0 + d + 1];
            xr0c = xb[roff0 + d + 2]; xr0d = xb[roff0 + d + 3];
            xr1a = xb[roff1 + d + 0]; xr1b = xb[roff1 + d + 1];
            xr1c = xb[roff1 + d + 2]; xr1d = xb[roff1 + d + 3];
        }
        __syncthreads();

        float4v oacc0 = zf, oacc1 = zf;
        float l0 = 0.f, l1 = 0.f;
        half8 kvc = *(const half8*)&buf[cur][0][lane][0];
#pragma unroll 4
        for (int t = 0; t < 16; ++t) {
            const half8 kvn = *(const half8*)&buf[cur][(t + 1) & 15][lane][0];
            const half4 kf = __builtin_shufflevector(kvc, kvc, 0, 1, 2, 3);
            const half4 vf = __builtin_shufflevector(kvc, kvc, 4, 5, 6, 7);
            const float4v s0 = __builtin_amdgcn_mfma_f32_16x16x16f16(kf, qfr0, zf, 0, 0, 0);
            const float4v s1 = __builtin_amdgcn_mfma_f32_16x16x16f16(kf, qfr1, zf, 0, 0, 0);
            const float p00 = __builtin_amdgcn_exp2f(s0[0]);
            const float p01 = __builtin_amdgcn_exp2f(s0[1]);
            const float p02 = __builtin_amdgcn_exp2f(s0[2]);
            const float p03 = __builtin_amdgcn_exp2f(s0[3]);
            l0 += (p00 + p01) + (p02 + p03);
            oacc0 = __builtin_amdgcn_mfma_f32_16x16x16f16(
                vf, mk_half4(p00, p01, p02, p03), oacc0, 0, 0, 0);
            const float p10 = __builtin_amdgcn_exp2f(s1[0]);
            const float p11 = __builtin_amdgcn_exp2f(s1[1]);
            const float p12 = __builtin_amdgcn_exp2f(s1[2]);
            const float p13 = __builtin_amdgcn_exp2f(s1[3]);
            l1 += (p10 + p11) + (p12 + p13);
            oacc1 = __builtin_amdgcn_mfma_f32_16x16x16f16(
                vf, mk_half4(p10, p11, p12, p13), oacc1, 0, 0, 0);
            kvc = kvn;
        }
#pragma unroll
        for (int u = 0; u < 2; ++u) {
            float lj = u ? l1 : l0;
            lj += __shfl_xor(lj, 16, 64);
            lj += __shfl_xor(lj, 32, 64);
            const float rl = __builtin_amdgcn_rcpf(lj);
            const float4v oa = u ? oacc1 : oacc0;
            const int r = 8 * wave + 4 * u + (o >> 2);
            const int c = 16 * (o & 3) + 4 * g + jj;
            fold[r][c + 0] += oa[0] * rl;
            fold[r][c + 1] += oa[1] * rl;
            fold[r][c + 2] += oa[2] * rl;
            fold[r][c + 3] += oa[3] * rl;
        }
    }
    __syncthreads();

    float* ob = out + ((size_t)bc * HWDIM + ii) * HWDIM;
    for (int i = tid; i < 64 * HWDIM; i += 512) {
        atomicAdd(&ob[i], fold[i / HWDIM][i % HWDIM]);
    }
}

extern "C" void kernel_launch(void* const* d_in, const int* in_sizes, int n_in,
                              void* d_out, int out_size, void* d_ws, size_t ws_size,
                              hipStream_t stream) {
    const float* x = (const float*)d_in[0];
    const float* w = (const float*)d_in[1];
    float* out = (float*)d_out;
    (void)in_sizes; (void)n_in;

    const size_t need = (size_t)BATCH * CHAN * 16 * PLANE * sizeof(_Float16); // 16.8 MB
    if (ws_size >= need) {
        _Float16* ao = (_Float16*)d_ws;
        ska_attn<<<BATCH * CHAN * 8, 256, 0, stream>>>(x, w, ao);
        ska_sum<<<(OUT_TOTAL + 255) / 256, 256, 0, stream>>>(ao, out);
    } else {
        (void)hipMemsetAsync(out, 0, (size_t)out_size * sizeof(float), stream);
        ska_fused_atomic<<<BATCH * CHAN * 4, 512, 0, stream>>>(x, w, out);
    }
}

// Round 13
// 78.884 us; speedup vs baseline: 1.2113x; 1.2107x over previous
//
#include <hip/hip_runtime.h>

// SlidingKernelAttention: unfold(k=4,s=1) -> per-(b,c,patch-offset) attention
// over seq=256 tokens of dim=16 -> overlap-add fold.
// B=2, C=64, H=W=67, Ho=Wo=64, N = B*C*16 = 2048 independent sequences.
//
// R22 = R17 (empirical best: 80.8us total, ~40us controllable) + the one
// verified micro-win from R21: softmax denominator via ones-MFMA.
// Structure ledger (R17-R21): fused LDS engine ~40us controllable beats
// atomic-free 4-blk/CU split (~43), two-pass (~42.5), barrier-free
// register-resident (~51, same at 2 and 4 waves/SIMD -> barrier-coupling
// refuted). The ~23us above the ~16us issue floor is invariant to
// occupancy / barriers / atomics / instruction count / wave decomposition.
// Restoring the best structure; only change vs R17:
//   lacc = mfma(ones, pb, lacc)  — D = 1 * P^T puts the COMPLETE key-sum
//   for lane's query in every lacc reg (accumulated over t); deletes the
//   3 VALU adds/step (384/thread) and the epilogue shfl_xor chain; the
//   extra MFMA rides the 33%-utilized matrix pipe. Numerics verified in
//   R21 (absmax 0.015625, same as all passing rounds).
//
// Structure (R17): block=(bc,ii), 512 blocks x 512 thr (2 blocks/CU), 4
// planes (jj=0..3) serial per block, cross-plane x-prefetch (R15), KV
// double-buffered LDS (2x16KB), one barrier/plane, R11 2-q-tile main
// loop, wave-private fold rows -> plain LDS += (no LDS atomics), out
// pre-zeroed + global atomicAdd merge. LDS 49.7KB/block.
//
// MFMA layout identity (R5-R8, HW-verified): projection MFMA results ARE
// attention operands: K^T=Wk.X^T (A-frag), V=X.Wv^T (A-frag of V^T),
// Q^T=s.Wq.X^T (B-frag), P^T=exp2(S^T) (B-frag). C/D layout == B layout.
// X addressing (R13): lane (o,g) of tile t of plane (ii,jj) holds
// features 4g..4g+3 of token s=t*16+o at
//   x[bc][4t+(o>>2)+ii][16*(o&3)+4g+jj .. +3].
// Fold mapping (HW-verified R16-R18): query q=jq*16+o, feature idx of
// plane (ii,jj) adds to fold[4*jq+(o>>2)][16*(o&3)+4*g+idx+jj]; fold rows
// r=8*wave+4u+(o>>2) are wave-private. All fragments statically indexed
// (R4); f16 via v_cvt_pkrtz + bit_cast/shufflevector only (R8).
// Timed window includes the ~41-50us harness fill of the unused d_ws
// (unavoidable — runs even when d_ws untouched, R16).

#define BATCH 2
#define CHAN 64
#define HWDIM 67
#define SEQ 256
#define DIM 16
#define OUT_TOTAL (BATCH * CHAN * HWDIM * HWDIM)   // 574592
#define ATT_SCALE 0.70710678118654752f             // (DIM/HEADS)^-0.5
#define LOG2E 1.44269504088896340736f

typedef _Float16 half4 __attribute__((ext_vector_type(4)));
typedef _Float16 half8 __attribute__((ext_vector_type(8)));
typedef float float4v __attribute__((ext_vector_type(4)));
typedef __fp16 fp16x2 __attribute__((ext_vector_type(2)));
typedef unsigned int uint2v __attribute__((ext_vector_type(2)));

// 2x v_cvt_pkrtz + register-pair aliasing: zero insert/extract VALU.
static __device__ __forceinline__ half4 mk_half4(float a, float b, float c, float d) {
    fp16x2 lo = __builtin_amdgcn_cvt_pkrtz(a, b);
    fp16x2 hi = __builtin_amdgcn_cvt_pkrtz(c, d);
    uint2v u;
    u[0] = __builtin_bit_cast(unsigned int, lo);
    u[1] = __builtin_bit_cast(unsigned int, hi);
    return __builtin_bit_cast(half4, u);
}

static __device__ __forceinline__ half4 pack4(float4v c) {
    return mk_half4(c[0], c[1], c[2], c[3]);
}

// one q-tile step: exp2 the 4 scores, pack, accumulate O^T and (via the
// ones-MFMA) the softmax denominator. No VALU l-adds, no epilogue shfl.
static __device__ __forceinline__ void att_step2(const half4 vf, const half4 ones,
                                                 const float4v sfr,
                                                 float4v& lacc, float4v& oacc) {
    const float p0 = __builtin_amdgcn_exp2f(sfr[0]);
    const float p1 = __builtin_amdgcn_exp2f(sfr[1]);
    const float p2 = __builtin_amdgcn_exp2f(sfr[2]);
    const float p3 = __builtin_amdgcn_exp2f(sfr[3]);
    const half4 pb = mk_half4(p0, p1, p2, p3);
    oacc = __builtin_amdgcn_mfma_f32_16x16x16f16(vf, pb, oacc, 0, 0, 0);
    lacc = __builtin_amdgcn_mfma_f32_16x16x16f16(ones, pb, lacc, 0, 0, 0);
}

__global__ __launch_bounds__(512, 4) void ska_fused(
    const float* __restrict__ x,      // [B, C, 67, 67]
    const float* __restrict__ w,      // [48, 16]
    float* __restrict__ out)          // [B, C, 67, 67], pre-zeroed
{
    // KV double buffer (per plane) + block-private fold tile.
    // fold stride 69 (coprime with 32) to spread fold-RMW banks.
    __shared__ __align__(16) _Float16 buf[2][16][64][8];   // 32 KB
    __shared__ float fold[64][69];                          // 17.7 KB

    // XCD chunked swizzle: 512 blocks = 8 XCDs x 64 -> bc [16k,16k+16) on
    // XCD k; the 4 blocks of a bc share x[bc] (18KB) in one XCD's L2.
    const int b  = (int)(blockIdx.x & 7) * 64 + (int)(blockIdx.x >> 3);
    const int bc = b >> 2;
    const int ii = b & 3;          // patch-row offset of this block's planes

    const int tid  = threadIdx.x;
    const int wave = tid >> 6;     // 0..7: owns q/k tiles 2w, 2w+1
    const int lane = tid & 63;
    const int o = lane & 15;       // token-in-tile / weight output row
    const int g = lane >> 4;       // feature group (k-group)

    // zero the fold tile (first KV barrier below covers the hazard:
    // fold writes happen only after that barrier)
    {
        float* ff = &fold[0][0];
        for (int i = tid; i < 64 * 69; i += 512) ff[i] = 0.f;
    }

    // weight fragments straight from global (3 KB, L1-resident)
    const float4 wq4 = *(const float4*)(w + ( 0 + o) * DIM + 4 * g);
    const float4 wk4 = *(const float4*)(w + (16 + o) * DIM + 4 * g);
    const float4 wv4 = *(const float4*)(w + (32 + o) * DIM + 4 * g);
    const half4 wqf = mk_half4(wq4.x * (ATT_SCALE * LOG2E), wq4.y * (ATT_SCALE * LOG2E),
                               wq4.z * (ATT_SCALE * LOG2E), wq4.w * (ATT_SCALE * LOG2E));
    const half4 wkf = mk_half4(wk4.x, wk4.y, wk4.z, wk4.w);
    const half4 wvf = mk_half4(wv4.x, wv4.y, wv4.z, wv4.w);

    const float4v zf = (float4v){0.f, 0.f, 0.f, 0.f};
    const half4 ones = {(_Float16)1.f, (_Float16)1.f, (_Float16)1.f, (_Float16)1.f};

    // X addressing (R13/R15, HW-verified): lane (o,g) of tile t of plane
    // (ii,jj) holds features 4g..4g+3 of token s=t*16+o:
    //   x[bc][4t + (o>>2) + ii][16*(o&3) + 4g + jj .. +3]
    // Wave w owns tiles 2w, 2w+1 -> row offsets roff0/roff1.
    const float* xb = x + ((size_t)bc * HWDIM + ii) * HWDIM + (o & 3) * 16 + 4 * g;
    const int roff0 = (8 * wave + (o >> 2)) * HWDIM;
    const int roff1 = roff0 + 4 * HWDIM;

    // prefetch plane jj=0 (scalar loads; jj>0 addresses are 4B-aligned)
    float xr0a = xb[roff0 + 0], xr0b = xb[roff0 + 1],
          xr0c = xb[roff0 + 2], xr0d = xb[roff0 + 3];
    float xr1a = xb[roff1 + 0], xr1b = xb[roff1 + 1],
          xr1c = xb[roff1 + 2], xr1d = xb[roff1 + 3];

    for (int jj = 0; jj < 4; ++jj) {
        const int cur = jj & 1;

        // projection for plane jj from the prefetched x registers
        half4 qfr0, qfr1;
        {
            const half4 xf0 = mk_half4(xr0a, xr0b, xr0c, xr0d);
            const half4 kf0 = pack4(__builtin_amdgcn_mfma_f32_16x16x16f16(wkf, xf0, zf, 0, 0, 0));
            const half4 vf0 = pack4(__builtin_amdgcn_mfma_f32_16x16x16f16(xf0, wvf, zf, 0, 0, 0));
            *(half8*)&buf[cur][2 * wave][lane][0] =
                __builtin_shufflevector(kf0, vf0, 0, 1, 2, 3, 4, 5, 6, 7);
            qfr0 = pack4(__builtin_amdgcn_mfma_f32_16x16x16f16(wqf, xf0, zf, 0, 0, 0));

            const half4 xf1 = mk_half4(xr1a, xr1b, xr1c, xr1d);
            const half4 kf1 = pack4(__builtin_amdgcn_mfma_f32_16x16x16f16(wkf, xf1, zf, 0, 0, 0));
            const half4 vf1 = pack4(__builtin_amdgcn_mfma_f32_16x16x16f16(xf1, wvf, zf, 0, 0, 0));
            *(half8*)&buf[cur][2 * wave + 1][lane][0] =
                __builtin_shufflevector(kf1, vf1, 0, 1, 2, 3, 4, 5, 6, 7);
            qfr1 = pack4(__builtin_amdgcn_mfma_f32_16x16x16f16(wqf, xf1, zf, 0, 0, 0));
        }

        // issue next plane's x loads now (+1 column); consumed after this
        // plane's main loop -> latency hides under ~1.4us of compute.
        if (jj < 3) {
            const int d = jj + 1;
            xr0a = xb[roff0 + d + 0]; xr0b = xb[roff0 + d + 1];
            xr0c = xb[roff0 + d + 2]; xr0d = xb[roff0 + d + 3];
            xr1a = xb[roff1 + d + 0]; xr1b = xb[roff1 + d + 1];
            xr1c = xb[roff1 + d + 2]; xr1d = xb[roff1 + d + 3];
        }

        __syncthreads();   // kv frags of plane jj ready (one barrier/plane;
                           // also orders round-0 fold writes after zeroing)

        float4v oacc0 = zf, oacc1 = zf, lacc0 = zf, lacc1 = zf;

        // main loop (R11/R17 engine + ones-MFMA denominator): one
        // ds_read_b128 per k-tile, prefetched one tile ahead; 2 S-MFMAs
        // issue before the exp2/pack/O-MFMA phase.
        half8 kvc = *(const half8*)&buf[cur][0][lane][0];
#pragma unroll 4
        for (int t = 0; t < 16; ++t) {
            const half8 kvn = *(const half8*)&buf[cur][(t + 1) & 15][lane][0];
            const half4 kf = __builtin_shufflevector(kvc, kvc, 0, 1, 2, 3);
            const half4 vf = __builtin_shufflevector(kvc, kvc, 4, 5, 6, 7);
            const float4v s0 = __builtin_amdgcn_mfma_f32_16x16x16f16(kf, qfr0, zf, 0, 0, 0);
            const float4v s1 = __builtin_amdgcn_mfma_f32_16x16x16f16(kf, qfr1, zf, 0, 0, 0);
            att_step2(vf, ones, s0, lacc0, oacc0);
            att_step2(vf, ones, s1, lacc1, oacc1);
            kvc = kvn;
        }

        // fold. l is complete in every lacc reg (ones-MFMA k-dim spans all
        // 16 keys of each tile; accumulated over t) -> no cross-lane
        // reduce. Fold rows r = 8*wave+4u+(o>>2) are wave-private -> plain
        // += (no atomics).
#pragma unroll
        for (int u = 0; u < 2; ++u) {
            const float lj = u ? lacc1[0] : lacc0[0];
            const float rl = __builtin_amdgcn_rcpf(lj);
            const float4v oa = u ? oacc1 : oacc0;
            const int r = 8 * wave + 4 * u + (o >> 2);
            const int c = 16 * (o & 3) + 4 * g + jj;
            fold[r][c + 0] += oa[0] * rl;
            fold[r][c + 1] += oa[1] * rl;
            fold[r][c + 2] += oa[2] * rl;
            fold[r][c + 3] += oa[3] * rl;
        }
        // no trailing barrier: next projection writes buf[(jj+1)&1];
        // buf[jj&1] is reused only after the NEXT barrier (hazard-free,
        // R15 analysis). fold rows are wave-private across rounds.
    }

    __syncthreads();   // all planes folded

    // merge this block's 64x67 partial into out (pre-zeroed; the 4 blocks
    // of a bc overlap rows -> atomicAdd, ~4288/block)
    float* ob = out + ((size_t)bc * HWDIM + ii) * HWDIM;
    for (int i = tid; i < 64 * HWDIM; i += 512) {
        const int r = i / HWDIM;
        const int c = i % HWDIM;
        atomicAdd(&ob[r * HWDIM + c], fold[r][c]);
    }
}

extern "C" void kernel_launch(void* const* d_in, const int* in_sizes, int n_in,
                              void* d_out, int out_size, void* d_ws, size_t ws_size,
                              hipStream_t stream) {
    const float* x = (const float*)d_in[0];
    const float* w = (const float*)d_in[1];
    float* out = (float*)d_out;
    (void)d_ws; (void)ws_size; (void)in_sizes; (void)n_in;

    (void)hipMemsetAsync(out, 0, (size_t)out_size * sizeof(float), stream);
    ska_fused<<<BATCH * CHAN * 4, 512, 0, stream>>>(x, w, out);
}